// Round 10
// baseline (204.152 us; speedup 1.0000x reference)
//
#include <hip/hip_runtime.h>
#include <hip/hip_bf16.h>

#define NBATCH 16384
#define WPB 4          // waves (samples) per block
#define BLOCK 256      // proven config: ~38 KB LDS -> 4 blocks/CU, VGPR 64

typedef unsigned int u32;
typedef unsigned char u8;

#define ENC 2032.0f                 // 127 / 0.0625
#define DEC 4.92125984e-4f          // 0.0625 / 127
#define BIAS_SUM (4096.0f * DEC)    // 32 rows * 128 bias

__device__ __forceinline__ float clamp01(float x){ return fminf(fmaxf(x, 0.f), 1.f); }

// ============================================================================
// Phase 0: convert ft_w (40960x256 f32, 40 MB) -> biased-u8 table (10 MB).
// q = round(v*2032)+128 in [1,255]; decode v = (q-128)*DEC.
// ============================================================================
__global__ __launch_bounds__(256) void convert_ftw_u8(
    const float* __restrict__ src, u32* __restrict__ dst, int n4)
{
    int i = blockIdx.x * blockDim.x + threadIdx.x;
    const int stride = gridDim.x * blockDim.x;
    for (; i < n4; i += stride) {
        float4 v = ((const float4*)src)[i];
        int q0 = __float2int_rn(v.x * ENC) + 128;
        int q1 = __float2int_rn(v.y * ENC) + 128;
        int q2 = __float2int_rn(v.z * ENC) + 128;
        int q3 = __float2int_rn(v.w * ENC) + 128;
        q0 = max(0, min(255, q0)); q1 = max(0, min(255, q1));
        q2 = max(0, min(255, q2)); q3 = max(0, min(255, q3));
        dst[i] = (u32)q0 | ((u32)q1 << 8) | ((u32)q2 << 16) | ((u32)q3 << 24);
    }
}

// ============================================================================
// Main kernel. R9 body with (a) SWAR integer row accumulation, (b) split-tree
// l1 reduction (31+1 shfl instead of 192) + x1 via per-wave LDS broadcast.
// ============================================================================
__global__ __launch_bounds__(BLOCK, 4) void nnue_fwd_u8tab(
    const int* __restrict__ wi, const int* __restrict__ bi,
    const float* __restrict__ stm,
    const u8* __restrict__ tab, const float* __restrict__ ftb,
    const float* __restrict__ l1w, const float* __restrict__ l1b,
    const float* __restrict__ l2w, const float* __restrict__ l2b,
    const float* __restrict__ l3w, const float* __restrict__ l3b,
    float* __restrict__ out)
{
    __shared__ __align__(16) float l1w_s[16*512];   // 32 KB: half of l1_w per pass
    __shared__ float l2w_s[32*33];                  // +1 pad rows
    __shared__ float l1b_s[32], l2b_s[32], l3w_s[32];
    __shared__ __align__(16) float x1_s[WPB][32];   // per-wave x1 broadcast slot
    __shared__ int idx_s[WPB][64];

    const int tid  = threadIdx.x;
    const int lane = tid & 63;
    const int wv   = tid >> 6;
    const int s    = blockIdx.x * WPB + wv;        // sample id

    // ---- stage small weights + l1 pass-1 (rows 0..15) ----
    {
        const float4* src = (const float4*)l1w;    // 4096 float4; 2048 per pass
        float4* dst = (float4*)l1w_s;
        #pragma unroll
        for (int i = 0; i < 8; ++i) dst[tid + i*BLOCK] = src[tid + i*BLOCK];
    }
    for (int i = tid; i < 1024; i += BLOCK)
        l2w_s[(i >> 5)*33 + (i & 31)] = l2w[i];
    if (tid < 32) {
        l1b_s[tid] = l1b[tid];
        l2b_s[tid] = l2b[tid];
        l3w_s[tid] = l3w[tid];
    }
    {   // lanes 0-31: white idx, lanes 32-63: black idx
        int bse = s*32 + (lane & 31);
        idx_s[wv][lane] = (lane < 32) ? wi[bse] : bi[bse];
    }
    __syncthreads();

    const int chunk = lane & 31;   // this lane's dims: chunk*8 .. chunk*8+7
    const int hsel  = lane & 32;   // 0 = white half-wave, 32 = black

    // ---- embedding bag: SWAR u16x2 accumulation of 32 u8 rows ----
    u32 sA = 0, sB = 0, sC = 0, sD = 0;
    #pragma unroll 8
    for (int j = 0; j < 32; ++j) {
        int row = idx_s[wv][j + hsel];             // 2-addr broadcast, free
        uint2 w = *(const uint2*)(tab + (size_t)row*256 + chunk*8);   // 8 B
        sA += (w.x      ) & 0x00FF00FFu;           // dims 0,2
        sB += (w.x >> 8 ) & 0x00FF00FFu;           // dims 1,3
        sC += (w.y      ) & 0x00FF00FFu;           // dims 4,6
        sD += (w.y >> 8 ) & 0x00FF00FFu;           // dims 5,7
    }
    float acc[8];
    {
        float4 a = *(const float4*)(ftb + chunk*8);
        float4 b = *(const float4*)(ftb + chunk*8 + 4);
        acc[0] = fmaf((float)(sA & 0xFFFFu), DEC, a.x - BIAS_SUM);
        acc[1] = fmaf((float)(sB & 0xFFFFu), DEC, a.y - BIAS_SUM);
        acc[2] = fmaf((float)(sA >> 16    ), DEC, a.z - BIAS_SUM);
        acc[3] = fmaf((float)(sB >> 16    ), DEC, a.w - BIAS_SUM);
        acc[4] = fmaf((float)(sC & 0xFFFFu), DEC, b.x - BIAS_SUM);
        acc[5] = fmaf((float)(sD & 0xFFFFu), DEC, b.y - BIAS_SUM);
        acc[6] = fmaf((float)(sC >> 16    ), DEC, b.z - BIAS_SUM);
        acc[7] = fmaf((float)(sD >> 16    ), DEC, b.w - BIAS_SUM);
    }
    #pragma unroll
    for (int k = 0; k < 8; ++k) acc[k] = clamp01(acc[k]);

    // ---- stm swap: lane ends up holding hidden[lane*8 .. lane*8+7] ----
    const bool wf = stm[s] > 0.5f;
    float h[8];
    #pragma unroll
    for (int k = 0; k < 8; ++k) {
        float x = __shfl_xor(acc[k], 32, 64);
        h[k] = wf ? acc[k] : x;
    }

    // ---- l1 pass 1: outputs 0..15 ----
    float p[32];
    #pragma unroll
    for (int o = 0; o < 16; ++o) {
        float4 wa = *(const float4*)&l1w_s[o*512 + lane*8];
        float4 wb = *(const float4*)&l1w_s[o*512 + lane*8 + 4];
        p[o] = h[0]*wa.x + h[1]*wa.y + h[2]*wa.z + h[3]*wa.w
             + h[4]*wb.x + h[5]*wb.y + h[6]*wb.z + h[7]*wb.w;
    }
    __syncthreads();   // all waves done reading pass-1 weights

    // ---- stage l1 pass-2 (rows 16..31) ----
    {
        const float4* src = (const float4*)l1w;
        float4* dst = (float4*)l1w_s;
        #pragma unroll
        for (int i = 0; i < 8; ++i) dst[tid + i*BLOCK] = src[2048 + tid + i*BLOCK];
    }
    __syncthreads();

    #pragma unroll
    for (int o = 0; o < 16; ++o) {
        float4 wa = *(const float4*)&l1w_s[o*512 + lane*8];
        float4 wb = *(const float4*)&l1w_s[o*512 + lane*8 + 4];
        p[16+o] = h[0]*wa.x + h[1]*wa.y + h[2]*wa.z + h[3]*wa.w
                + h[4]*wb.x + h[5]*wb.y + h[6]*wb.z + h[7]*wb.w;
    }

    // ---- split-tree reduction: 31 shfl + 1 final, vs 192 full-butterfly ----
    // After 5 levels lane L holds output obr(L) = bitrev5(L) summed over its
    // 32-lane half; final d=32 completes the 64-lane sum.
    #pragma unroll
    for (int lvl = 0; lvl < 5; ++lvl) {
        const int d = 1 << lvl;
        const int n = 16 >> lvl;            // outputs kept after this level
        const bool hi = (lane & d) != 0;
        #pragma unroll
        for (int o = 0; o < n; ++o) {
            float send = hi ? p[o] : p[o + n];
            float recv = __shfl_xor(send, d, 64);
            p[o] = (hi ? p[o + n] : p[o]) + recv;
        }
    }
    float r1 = p[0] + __shfl_xor(p[0], 32, 64);

    const int obr = ((lane & 1) << 4) | ((lane & 2) << 2) | (lane & 4)
                  | ((lane >> 2) & 2) | ((lane >> 4) & 1);
    float x1v = clamp01(r1 + l1b_s[obr]);
    if ((lane & 32) == 0) x1_s[wv][obr] = x1v;   // same-wave LDS: no barrier

    // ---- l2: lane j (dup at j+32) owns output j; x1 via broadcast b128 ----
    const int j2 = lane & 31;
    float a2 = l2b_s[j2];
    #pragma unroll
    for (int ii = 0; ii < 8; ++ii) {
        float4 xv = *(const float4*)&x1_s[wv][ii*4];   // wave-uniform: broadcast
        a2 += xv.x * l2w_s[j2*33 + ii*4    ];
        a2 += xv.y * l2w_s[j2*33 + ii*4 + 1];
        a2 += xv.z * l2w_s[j2*33 + ii*4 + 2];
        a2 += xv.w * l2w_s[j2*33 + ii*4 + 3];
    }
    float x2 = clamp01(a2);

    // ---- l3: reduce 32 outputs within each half-wave ----
    float r = x2 * l3w_s[j2];
    #pragma unroll
    for (int d = 16; d >= 1; d >>= 1) r += __shfl_xor(r, d, 64);

    if (lane == 0) out[s] = r + l3b[0];
}

// ============================================================================
// Fallback: proven R2 monolithic f32 kernel (no ws needed).
// ============================================================================
__global__ __launch_bounds__(256, 4) void nnue_fwd_f32(
    const int* __restrict__ wi, const int* __restrict__ bi,
    const float* __restrict__ stm,
    const float* __restrict__ ftw, const float* __restrict__ ftb,
    const float* __restrict__ l1w, const float* __restrict__ l1b,
    const float* __restrict__ l2w, const float* __restrict__ l2b,
    const float* __restrict__ l3w, const float* __restrict__ l3b,
    float* __restrict__ out)
{
    __shared__ __align__(16) float l1w_s[16*512];
    __shared__ float l2w_s[32*33];
    __shared__ float l1b_s[32], l2b_s[32], l3w_s[32];
    __shared__ int idx_s[4][64];

    const int tid  = threadIdx.x;
    const int lane = tid & 63;
    const int wv   = tid >> 6;
    const int s    = blockIdx.x * 4 + wv;

    {
        const float4* src = (const float4*)l1w;
        float4* dst = (float4*)l1w_s;
        #pragma unroll
        for (int i = 0; i < 8; ++i) dst[tid + i*256] = src[tid + i*256];
    }
    for (int i = tid; i < 1024; i += 256)
        l2w_s[(i >> 5)*33 + (i & 31)] = l2w[i];
    if (tid < 32) {
        l1b_s[tid] = l1b[tid];
        l2b_s[tid] = l2b[tid];
        l3w_s[tid] = l3w[tid];
    }
    {
        int bse = s*32 + (lane & 31);
        idx_s[wv][lane] = (lane < 32) ? wi[bse] : bi[bse];
    }
    __syncthreads();

    const int chunk = lane & 31;
    const int hsel  = lane & 32;

    float acc[8];
    {
        float4 a = *(const float4*)(ftb + chunk*8);
        float4 b = *(const float4*)(ftb + chunk*8 + 4);
        acc[0]=a.x; acc[1]=a.y; acc[2]=a.z; acc[3]=a.w;
        acc[4]=b.x; acc[5]=b.y; acc[6]=b.z; acc[7]=b.w;
    }
    #pragma unroll 8
    for (int j = 0; j < 32; ++j) {
        int row = idx_s[wv][j + hsel];
        const float* rp = ftw + (size_t)row*256 + chunk*8;
        float4 a = *(const float4*)rp;
        float4 b = *(const float4*)(rp + 4);
        acc[0]+=a.x; acc[1]+=a.y; acc[2]+=a.z; acc[3]+=a.w;
        acc[4]+=b.x; acc[5]+=b.y; acc[6]+=b.z; acc[7]+=b.w;
    }
    #pragma unroll
    for (int k = 0; k < 8; ++k) acc[k] = clamp01(acc[k]);

    const bool wf = stm[s] > 0.5f;
    float h[8];
    #pragma unroll
    for (int k = 0; k < 8; ++k) {
        float x = __shfl_xor(acc[k], 32, 64);
        h[k] = wf ? acc[k] : x;
    }

    float p[32];
    #pragma unroll
    for (int o = 0; o < 16; ++o) {
        float4 wa = *(const float4*)&l1w_s[o*512 + lane*8];
        float4 wb = *(const float4*)&l1w_s[o*512 + lane*8 + 4];
        p[o] = h[0]*wa.x + h[1]*wa.y + h[2]*wa.z + h[3]*wa.w
             + h[4]*wb.x + h[5]*wb.y + h[6]*wb.z + h[7]*wb.w;
    }
    __syncthreads();
    {
        const float4* src = (const float4*)l1w;
        float4* dst = (float4*)l1w_s;
        #pragma unroll
        for (int i = 0; i < 8; ++i) dst[tid + i*256] = src[2048 + tid + i*256];
    }
    __syncthreads();
    #pragma unroll
    for (int o = 0; o < 16; ++o) {
        float4 wa = *(const float4*)&l1w_s[o*512 + lane*8];
        float4 wb = *(const float4*)&l1w_s[o*512 + lane*8 + 4];
        p[16+o] = h[0]*wa.x + h[1]*wa.y + h[2]*wa.z + h[3]*wa.w
                + h[4]*wb.x + h[5]*wb.y + h[6]*wb.z + h[7]*wb.w;
    }
    #pragma unroll
    for (int o = 0; o < 32; ++o) {
        #pragma unroll
        for (int d = 1; d < 64; d <<= 1)
            p[o] += __shfl_xor(p[o], d, 64);
    }
    float x1[32];
    #pragma unroll
    for (int o = 0; o < 32; ++o) x1[o] = clamp01(p[o] + l1b_s[o]);

    const int j2 = lane & 31;
    float a2 = l2b_s[j2];
    #pragma unroll
    for (int i = 0; i < 32; ++i) a2 += x1[i] * l2w_s[j2*33 + i];
    float x2 = clamp01(a2);

    float r = x2 * l3w_s[j2];
    #pragma unroll
    for (int d = 16; d >= 1; d >>= 1) r += __shfl_xor(r, d, 64);

    if (lane == 0) out[s] = r + l3b[0];
}

extern "C" void kernel_launch(void* const* d_in, const int* in_sizes, int n_in,
                              void* d_out, int out_size, void* d_ws, size_t ws_size,
                              hipStream_t stream)
{
    const int*   wi  = (const int*)d_in[0];
    const int*   bi  = (const int*)d_in[2];
    const float* stm = (const float*)d_in[4];
    const float* ftw = (const float*)d_in[5];
    const float* ftb = (const float*)d_in[6];
    const float* l1w = (const float*)d_in[7];
    const float* l1b = (const float*)d_in[8];
    const float* l2w = (const float*)d_in[9];
    const float* l2b = (const float*)d_in[10];
    const float* l3w = (const float*)d_in[11];
    const float* l3b = (const float*)d_in[12];

    const size_t tab_elems = (size_t)40960 * 256;              // 10.5 M
    const size_t need = tab_elems * sizeof(u8);                // 10 MB
    if (ws_size >= need) {
        u8* tab = (u8*)d_ws;
        convert_ftw_u8<<<dim3(4096), dim3(256), 0, stream>>>(
            ftw, (u32*)tab, (int)(tab_elems / 4));
        nnue_fwd_u8tab<<<dim3(NBATCH / WPB), dim3(BLOCK), 0, stream>>>(
            wi, bi, stm, tab, ftb, l1w, l1b, l2w, l2b, l3w, l3b,
            (float*)d_out);
    } else {
        nnue_fwd_f32<<<dim3(NBATCH / 4), dim3(256), 0, stream>>>(
            wi, bi, stm, ftw, ftb, l1w, l1b, l2w, l2b, l3w, l3b,
            (float*)d_out);
    }
}

// Round 11
// 169.704 us; speedup vs baseline: 1.2030x; 1.2030x over previous
//
#include <hip/hip_runtime.h>
#include <hip/hip_bf16.h>

#define NBATCH 16384
#define WPB 4          // waves (samples) per block
#define BLOCK 256      // proven config: ~38 KB LDS -> 4 blocks/CU, VGPR 64

typedef unsigned int u32;
typedef unsigned char u8;

#define ENC 2032.0f                 // 127 / 0.0625
#define DEC 4.92125984e-4f          // 0.0625 / 127
#define BIAS_SUM (4096.0f * DEC)    // 32 rows * 128 bias

__device__ __forceinline__ float clamp01(float x){ return fminf(fmaxf(x, 0.f), 1.f); }

// ============================================================================
// Phase 0: convert ft_w (40960x256 f32, 40 MB) -> biased-u8 table (10 MB).
// q = round(v*2032)+128 in [1,255]; decode v = (q-128)*DEC.
// ============================================================================
__global__ __launch_bounds__(256) void convert_ftw_u8(
    const float* __restrict__ src, u32* __restrict__ dst, int n4)
{
    int i = blockIdx.x * blockDim.x + threadIdx.x;
    const int stride = gridDim.x * blockDim.x;
    for (; i < n4; i += stride) {
        float4 v = ((const float4*)src)[i];
        int q0 = __float2int_rn(v.x * ENC) + 128;
        int q1 = __float2int_rn(v.y * ENC) + 128;
        int q2 = __float2int_rn(v.z * ENC) + 128;
        int q3 = __float2int_rn(v.w * ENC) + 128;
        q0 = max(0, min(255, q0)); q1 = max(0, min(255, q1));
        q2 = max(0, min(255, q2)); q3 = max(0, min(255, q3));
        dst[i] = (u32)q0 | ((u32)q1 << 8) | ((u32)q2 << 16) | ((u32)q3 << 24);
    }
}

// ============================================================================
// Main kernel: R9 body verbatim, except the gather loop uses SWAR u16x2
// integer accumulation (8 VALU/row vs 16; exact integer sums, one fma decode).
// R9's butterfly/l2/l3 epilogue untouched (R10 lesson: don't perturb p[32]).
// ============================================================================
__global__ __launch_bounds__(BLOCK, 4) void nnue_fwd_u8tab(
    const int* __restrict__ wi, const int* __restrict__ bi,
    const float* __restrict__ stm,
    const u8* __restrict__ tab, const float* __restrict__ ftb,
    const float* __restrict__ l1w, const float* __restrict__ l1b,
    const float* __restrict__ l2w, const float* __restrict__ l2b,
    const float* __restrict__ l3w, const float* __restrict__ l3b,
    float* __restrict__ out)
{
    __shared__ __align__(16) float l1w_s[16*512];   // 32 KB: half of l1_w per pass
    __shared__ float l2w_s[32*33];                  // +1 pad rows
    __shared__ float l1b_s[32], l2b_s[32], l3w_s[32];
    __shared__ int idx_s[WPB][64];

    const int tid  = threadIdx.x;
    const int lane = tid & 63;
    const int wv   = tid >> 6;
    const int s    = blockIdx.x * WPB + wv;        // sample id

    // ---- stage small weights + l1 pass-1 (rows 0..15) ----
    {
        const float4* src = (const float4*)l1w;    // 4096 float4; 2048 per pass
        float4* dst = (float4*)l1w_s;
        #pragma unroll
        for (int i = 0; i < 8; ++i) dst[tid + i*BLOCK] = src[tid + i*BLOCK];
    }
    for (int i = tid; i < 1024; i += BLOCK)
        l2w_s[(i >> 5)*33 + (i & 31)] = l2w[i];
    if (tid < 32) {
        l1b_s[tid] = l1b[tid];
        l2b_s[tid] = l2b[tid];
        l3w_s[tid] = l3w[tid];
    }
    {   // lanes 0-31: white idx, lanes 32-63: black idx
        int bse = s*32 + (lane & 31);
        idx_s[wv][lane] = (lane < 32) ? wi[bse] : bi[bse];
    }
    __syncthreads();

    const int chunk = lane & 31;   // this lane's dims: chunk*8 .. chunk*8+7
    const int hsel  = lane & 32;   // 0 = white half-wave, 32 = black

    // ---- embedding bag: SWAR u16x2 accumulation of 32 u8 rows ----
    // max sum 32*255 = 8160 << 65536: no carry between u16 halves.
    u32 sA = 0, sB = 0, sC = 0, sD = 0;
    #pragma unroll 8
    for (int j = 0; j < 32; ++j) {
        int row = idx_s[wv][j + hsel];             // 2-addr broadcast, free
        uint2 w = *(const uint2*)(tab + (size_t)row*256 + chunk*8);   // 8 B
        sA += (w.x      ) & 0x00FF00FFu;           // dims 0,2
        sB += (w.x >> 8 ) & 0x00FF00FFu;           // dims 1,3
        sC += (w.y      ) & 0x00FF00FFu;           // dims 4,6
        sD += (w.y >> 8 ) & 0x00FF00FFu;           // dims 5,7
    }
    float acc[8];
    {
        float4 a = *(const float4*)(ftb + chunk*8);
        float4 b = *(const float4*)(ftb + chunk*8 + 4);
        acc[0] = fmaf((float)(sA & 0xFFFFu), DEC, a.x - BIAS_SUM);
        acc[1] = fmaf((float)(sB & 0xFFFFu), DEC, a.y - BIAS_SUM);
        acc[2] = fmaf((float)(sA >> 16    ), DEC, a.z - BIAS_SUM);
        acc[3] = fmaf((float)(sB >> 16    ), DEC, a.w - BIAS_SUM);
        acc[4] = fmaf((float)(sC & 0xFFFFu), DEC, b.x - BIAS_SUM);
        acc[5] = fmaf((float)(sD & 0xFFFFu), DEC, b.y - BIAS_SUM);
        acc[6] = fmaf((float)(sC >> 16    ), DEC, b.z - BIAS_SUM);
        acc[7] = fmaf((float)(sD >> 16    ), DEC, b.w - BIAS_SUM);
    }
    #pragma unroll
    for (int k = 0; k < 8; ++k) acc[k] = clamp01(acc[k]);

    // ---- stm swap: lane ends up holding hidden[lane*8 .. lane*8+7] ----
    const bool wf = stm[s] > 0.5f;
    float h[8];
    #pragma unroll
    for (int k = 0; k < 8; ++k) {
        float x = __shfl_xor(acc[k], 32, 64);
        h[k] = wf ? acc[k] : x;
    }

    // ---- l1 pass 1: outputs 0..15 ----
    float p[32];
    #pragma unroll
    for (int o = 0; o < 16; ++o) {
        float4 wa = *(const float4*)&l1w_s[o*512 + lane*8];
        float4 wb = *(const float4*)&l1w_s[o*512 + lane*8 + 4];
        p[o] = h[0]*wa.x + h[1]*wa.y + h[2]*wa.z + h[3]*wa.w
             + h[4]*wb.x + h[5]*wb.y + h[6]*wb.z + h[7]*wb.w;
    }
    __syncthreads();   // all waves done reading pass-1 weights

    // ---- stage l1 pass-2 (rows 16..31) ----
    {
        const float4* src = (const float4*)l1w;
        float4* dst = (float4*)l1w_s;
        #pragma unroll
        for (int i = 0; i < 8; ++i) dst[tid + i*BLOCK] = src[2048 + tid + i*BLOCK];
    }
    __syncthreads();

    #pragma unroll
    for (int o = 0; o < 16; ++o) {
        float4 wa = *(const float4*)&l1w_s[o*512 + lane*8];
        float4 wb = *(const float4*)&l1w_s[o*512 + lane*8 + 4];
        p[16+o] = h[0]*wa.x + h[1]*wa.y + h[2]*wa.z + h[3]*wa.w
                + h[4]*wb.x + h[5]*wb.y + h[6]*wb.z + h[7]*wb.w;
    }

    // ---- full 64-lane butterfly: every lane gets all 32 sums ----
    #pragma unroll
    for (int o = 0; o < 32; ++o) {
        #pragma unroll
        for (int d = 1; d < 64; d <<= 1)
            p[o] += __shfl_xor(p[o], d, 64);
    }
    float x1[32];
    #pragma unroll
    for (int o = 0; o < 32; ++o) x1[o] = clamp01(p[o] + l1b_s[o]);

    // ---- l2: lane j (dup at j+32) owns output j ----
    const int j2 = lane & 31;
    float a2 = l2b_s[j2];
    #pragma unroll
    for (int i = 0; i < 32; ++i) a2 += x1[i] * l2w_s[j2*33 + i];
    float x2 = clamp01(a2);

    // ---- l3: reduce 32 outputs within each half-wave ----
    float r = x2 * l3w_s[j2];
    #pragma unroll
    for (int d = 16; d >= 1; d >>= 1) r += __shfl_xor(r, d, 64);

    if (lane == 0) out[s] = r + l3b[0];
}

// ============================================================================
// Fallback: proven R2 monolithic f32 kernel (no ws needed).
// ============================================================================
__global__ __launch_bounds__(256, 4) void nnue_fwd_f32(
    const int* __restrict__ wi, const int* __restrict__ bi,
    const float* __restrict__ stm,
    const float* __restrict__ ftw, const float* __restrict__ ftb,
    const float* __restrict__ l1w, const float* __restrict__ l1b,
    const float* __restrict__ l2w, const float* __restrict__ l2b,
    const float* __restrict__ l3w, const float* __restrict__ l3b,
    float* __restrict__ out)
{
    __shared__ __align__(16) float l1w_s[16*512];
    __shared__ float l2w_s[32*33];
    __shared__ float l1b_s[32], l2b_s[32], l3w_s[32];
    __shared__ int idx_s[4][64];

    const int tid  = threadIdx.x;
    const int lane = tid & 63;
    const int wv   = tid >> 6;
    const int s    = blockIdx.x * 4 + wv;

    {
        const float4* src = (const float4*)l1w;
        float4* dst = (float4*)l1w_s;
        #pragma unroll
        for (int i = 0; i < 8; ++i) dst[tid + i*256] = src[tid + i*256];
    }
    for (int i = tid; i < 1024; i += 256)
        l2w_s[(i >> 5)*33 + (i & 31)] = l2w[i];
    if (tid < 32) {
        l1b_s[tid] = l1b[tid];
        l2b_s[tid] = l2b[tid];
        l3w_s[tid] = l3w[tid];
    }
    {
        int bse = s*32 + (lane & 31);
        idx_s[wv][lane] = (lane < 32) ? wi[bse] : bi[bse];
    }
    __syncthreads();

    const int chunk = lane & 31;
    const int hsel  = lane & 32;

    float acc[8];
    {
        float4 a = *(const float4*)(ftb + chunk*8);
        float4 b = *(const float4*)(ftb + chunk*8 + 4);
        acc[0]=a.x; acc[1]=a.y; acc[2]=a.z; acc[3]=a.w;
        acc[4]=b.x; acc[5]=b.y; acc[6]=b.z; acc[7]=b.w;
    }
    #pragma unroll 8
    for (int j = 0; j < 32; ++j) {
        int row = idx_s[wv][j + hsel];
        const float* rp = ftw + (size_t)row*256 + chunk*8;
        float4 a = *(const float4*)rp;
        float4 b = *(const float4*)(rp + 4);
        acc[0]+=a.x; acc[1]+=a.y; acc[2]+=a.z; acc[3]+=a.w;
        acc[4]+=b.x; acc[5]+=b.y; acc[6]+=b.z; acc[7]+=b.w;
    }
    #pragma unroll
    for (int k = 0; k < 8; ++k) acc[k] = clamp01(acc[k]);

    const bool wf = stm[s] > 0.5f;
    float h[8];
    #pragma unroll
    for (int k = 0; k < 8; ++k) {
        float x = __shfl_xor(acc[k], 32, 64);
        h[k] = wf ? acc[k] : x;
    }

    float p[32];
    #pragma unroll
    for (int o = 0; o < 16; ++o) {
        float4 wa = *(const float4*)&l1w_s[o*512 + lane*8];
        float4 wb = *(const float4*)&l1w_s[o*512 + lane*8 + 4];
        p[o] = h[0]*wa.x + h[1]*wa.y + h[2]*wa.z + h[3]*wa.w
             + h[4]*wb.x + h[5]*wb.y + h[6]*wb.z + h[7]*wb.w;
    }
    __syncthreads();
    {
        const float4* src = (const float4*)l1w;
        float4* dst = (float4*)l1w_s;
        #pragma unroll
        for (int i = 0; i < 8; ++i) dst[tid + i*256] = src[2048 + tid + i*256];
    }
    __syncthreads();
    #pragma unroll
    for (int o = 0; o < 16; ++o) {
        float4 wa = *(const float4*)&l1w_s[o*512 + lane*8];
        float4 wb = *(const float4*)&l1w_s[o*512 + lane*8 + 4];
        p[16+o] = h[0]*wa.x + h[1]*wa.y + h[2]*wa.z + h[3]*wa.w
                + h[4]*wb.x + h[5]*wb.y + h[6]*wb.z + h[7]*wb.w;
    }
    #pragma unroll
    for (int o = 0; o < 32; ++o) {
        #pragma unroll
        for (int d = 1; d < 64; d <<= 1)
            p[o] += __shfl_xor(p[o], d, 64);
    }
    float x1[32];
    #pragma unroll
    for (int o = 0; o < 32; ++o) x1[o] = clamp01(p[o] + l1b_s[o]);

    const int j2 = lane & 31;
    float a2 = l2b_s[j2];
    #pragma unroll
    for (int i = 0; i < 32; ++i) a2 += x1[i] * l2w_s[j2*33 + i];
    float x2 = clamp01(a2);

    float r = x2 * l3w_s[j2];
    #pragma unroll
    for (int d = 16; d >= 1; d >>= 1) r += __shfl_xor(r, d, 64);

    if (lane == 0) out[s] = r + l3b[0];
}

extern "C" void kernel_launch(void* const* d_in, const int* in_sizes, int n_in,
                              void* d_out, int out_size, void* d_ws, size_t ws_size,
                              hipStream_t stream)
{
    const int*   wi  = (const int*)d_in[0];
    const int*   bi  = (const int*)d_in[2];
    const float* stm = (const float*)d_in[4];
    const float* ftw = (const float*)d_in[5];
    const float* ftb = (const float*)d_in[6];
    const float* l1w = (const float*)d_in[7];
    const float* l1b = (const float*)d_in[8];
    const float* l2w = (const float*)d_in[9];
    const float* l2b = (const float*)d_in[10];
    const float* l3w = (const float*)d_in[11];
    const float* l3b = (const float*)d_in[12];

    const size_t tab_elems = (size_t)40960 * 256;              // 10.5 M
    const size_t need = tab_elems * sizeof(u8);                // 10 MB
    if (ws_size >= need) {
        u8* tab = (u8*)d_ws;
        convert_ftw_u8<<<dim3(4096), dim3(256), 0, stream>>>(
            ftw, (u32*)tab, (int)(tab_elems / 4));
        nnue_fwd_u8tab<<<dim3(NBATCH / WPB), dim3(BLOCK), 0, stream>>>(
            wi, bi, stm, tab, ftb, l1w, l1b, l2w, l2b, l3w, l3b,
            (float*)d_out);
    } else {
        nnue_fwd_f32<<<dim3(NBATCH / 4), dim3(256), 0, stream>>>(
            wi, bi, stm, ftw, ftb, l1w, l1b, l2w, l2b, l3w, l3b,
            (float*)d_out);
    }
}